// Round 14
// baseline (139.862 us; speedup 1.0000x reference)
//
#include <hip/hip_runtime.h>

// OurButterflyLayer: N=4096, LOGN=12, IN=1024, OUT=4096, BATCH=8192
//
// out[s,j] = scale[j] * z_s[src[j]],  z_s = 10-stage butterfly (stages 0..9)
// on the 1024-float input row s; stages 10,11 + out-row gather fold into
// per-output (scale, src) pairs (elements >=1024 stay zero through stages
// 0..9 since all strides < 1024).
//
// Round-14: persistent blocks + split-chunk pipeline on the R13 base.
// grid 256 x 512 thr = exactly 1 block/CU (coeffs staged once per CU, no
// block handoff). Wave owns 4 samples as 2 chunks:
//   bf(c0) -> zwrite0 -> issue c1 input loads -> emit0 (stores || loads)
//   -> bf(c1) (|| c0 stores drain) -> zwrite1 -> emit1.
// All 20 coeff rows in 80 KB swizzled LDS; 8 KB/wave paired-z scratch.
// Butterfly/exchange/slot/epilogue bodies = R13 verified code. Plain
// loads/stores. Chunk-1 loads issued late to cap register pressure
// (R11's regression = spills from holding both chunks live).

typedef float f4 __attribute__((ext_vector_type(4)));
typedef float f2 __attribute__((ext_vector_type(2)));
typedef int   i4 __attribute__((ext_vector_type(4)));

__device__ __forceinline__ int swz(int e) {
    // XOR float-index bits [6:5] into [3:2]: keeps float4 alignment; makes
    // 64B-stride LDS coeff accesses bank-conflict-free.
    return e ^ (((e >> 5) & 3) << 2);
}

template<int CTRL>
__device__ __forceinline__ float dppx(float x) {
    int xi = __builtin_bit_cast(int, x);
    int r  = __builtin_amdgcn_update_dpp(xi, xi, CTRL, 0xF, 0xF, true);
    return __builtin_bit_cast(float, r);
}
// ctrl: quad_perm(1,0,3,2)=0xB1 (lane^1), quad_perm(2,3,0,1)=0x4E (lane^2),
// row_ror:8=0x128 (lane^8 within 16-lane row). Verified R4/R6/R7/R10/R13.

__global__ void __launch_bounds__(256) bfly_prep(
    const float* __restrict__ lp, const int* __restrict__ orow,
    float* __restrict__ scale, int* __restrict__ src2)
{
    int j = blockIdx.x * 256 + threadIdx.x;
    if (j >= 4096) return;
    int r = orow[j];
    int c = r & 1023;
    int u = r & 2047;
    const float* A10 = lp + 20 * 4096;
    const float* B10 = lp + 21 * 4096;
    const float* A11 = lp + 22 * 4096;
    const float* B11 = lp + 23 * 4096;
    float f11 = (r & 2048) ? B11[u] : A11[u];
    float f10 = (r & 1024) ? B10[c] : A10[c];
    scale[j] = f11 * f10;
    // f2-slot index with pair-preserving bank spread:
    // pz(c) = c ^ (((c>>4)&7)<<1)   (matches z-write slot algebra below)
    src2[j] = c ^ (((c >> 4) & 7) << 1);
}

__device__ __forceinline__ void load_chunk(
    const float* __restrict__ inp, int s0, int lane, float (&x)[2][16])
{
    #pragma unroll
    for (int m = 0; m < 2; ++m) {
        const f4* p = reinterpret_cast<const f4*>(inp + (size_t)(s0 + m) * 1024 + lane * 16);
        #pragma unroll
        for (int c = 0; c < 4; ++c) {
            f4 v = p[c];
            x[m][4*c+0] = v.x; x[m][4*c+1] = v.y; x[m][4*c+2] = v.z; x[m][4*c+3] = v.w;
        }
    }
}

__device__ __forceinline__ void butterfly(
    const float* __restrict__ cf, int lane, float (&x)[2][16])
{
    // ---- stages 0,1 (s=1,2): pairs within each f4 quarter ----
    #pragma unroll
    for (int i = 0; i < 2; ++i) {
        const float* arow = &cf[(size_t)(2*i)     * 1024];
        const float* brow = &cf[(size_t)(2*i + 1) * 1024];
        #pragma unroll
        for (int c = 0; c < 4; ++c) {
            f4 va = *reinterpret_cast<const f4*>(&arow[swz(lane * 16 + 4 * c)]);
            f4 vb = *reinterpret_cast<const f4*>(&brow[swz(lane * 16 + 4 * c)]);
            #pragma unroll
            for (int m = 0; m < 2; ++m) {
                float* xm = x[m];
                if (i == 0) {          // pairs (0,1),(2,3)
                    float lo0 = xm[4*c+0], hi0 = xm[4*c+1];
                    xm[4*c+0] = va[0] * lo0 + vb[1] * hi0;
                    xm[4*c+1] = va[1] * hi0 + vb[0] * lo0;
                    float lo1 = xm[4*c+2], hi1 = xm[4*c+3];
                    xm[4*c+2] = va[2] * lo1 + vb[3] * hi1;
                    xm[4*c+3] = va[3] * hi1 + vb[2] * lo1;
                } else {               // pairs (0,2),(1,3)
                    float lo0 = xm[4*c+0], hi0 = xm[4*c+2];
                    xm[4*c+0] = va[0] * lo0 + vb[2] * hi0;
                    xm[4*c+2] = va[2] * hi0 + vb[0] * lo0;
                    float lo1 = xm[4*c+1], hi1 = xm[4*c+3];
                    xm[4*c+1] = va[1] * lo1 + vb[3] * hi1;
                    xm[4*c+3] = va[3] * hi1 + vb[1] * lo1;
                }
            }
        }
    }

    // ---- stages 2,3 (s=4,8): pairs across quarters ----
    #pragma unroll
    for (int i = 2; i < 4; ++i) {
        const float* arow = &cf[(size_t)(2*i)     * 1024];
        const float* brow = &cf[(size_t)(2*i + 1) * 1024];
        #pragma unroll
        for (int g = 0; g < 2; ++g) {
            const int q0 = (i == 2) ? 2 * g : g;       // s=4: (0,1),(2,3)
            const int q1 = (i == 2) ? q0 + 1 : q0 + 2; // s=8: (0,2),(1,3)
            f4 va0 = *reinterpret_cast<const f4*>(&arow[swz(lane * 16 + 4 * q0)]);
            f4 va1 = *reinterpret_cast<const f4*>(&arow[swz(lane * 16 + 4 * q1)]);
            f4 vb0 = *reinterpret_cast<const f4*>(&brow[swz(lane * 16 + 4 * q0)]);
            f4 vb1 = *reinterpret_cast<const f4*>(&brow[swz(lane * 16 + 4 * q1)]);
            #pragma unroll
            for (int m = 0; m < 2; ++m) {
                float* xm = x[m];
                #pragma unroll
                for (int e = 0; e < 4; ++e) {
                    float lo = xm[4*q0+e], hi = xm[4*q1+e];
                    xm[4*q0+e] = va0[e] * lo + vb1[e] * hi;
                    xm[4*q1+e] = va1[e] * hi + vb0[e] * lo;
                }
            }
        }
    }

    // ---- stage 4 (d=1): DPP quad_perm exchange; coeff rows 8,9 ----
    {
        const float* arow = &cf[(size_t)8 * 1024];
        const float* brow = &cf[(size_t)9 * 1024];
        #pragma unroll
        for (int c = 0; c < 4; ++c) {
            f4 va = *reinterpret_cast<const f4*>(&arow[swz(lane * 16 + 4 * c)]);
            f4 vb = *reinterpret_cast<const f4*>(&brow[swz((lane ^ 1) * 16 + 4 * c)]);
            #pragma unroll
            for (int m = 0; m < 2; ++m) {
                #pragma unroll
                for (int e = 0; e < 4; ++e) {
                    float v = x[m][4*c+e];
                    x[m][4*c+e] = va[e] * v + vb[e] * dppx<0xB1>(v);
                }
            }
        }
    }

    // ---- stages 5..9 (d=2,4,8,16,32): coeff rows 10..19 ----
    #pragma unroll
    for (int i = 5; i < 10; ++i) {
        const int d = 1 << (i - 4);
        const float* arow = &cf[(size_t)(2*i)     * 1024];
        const float* brow = &cf[(size_t)(2*i + 1) * 1024];
        #pragma unroll
        for (int c = 0; c < 4; ++c) {
            f4 va = *reinterpret_cast<const f4*>(&arow[swz(lane * 16 + 4 * c)]);
            f4 vb = *reinterpret_cast<const f4*>(&brow[swz((lane ^ d) * 16 + 4 * c)]);
            #pragma unroll
            for (int m = 0; m < 2; ++m) {
                #pragma unroll
                for (int e = 0; e < 4; ++e) {
                    float v = x[m][4*c+e];
                    float xp = (d == 2) ? dppx<0x4E>(v)
                             : (d == 8) ? dppx<0x128>(v)
                             :            __shfl_xor(v, d, 64);   // d = 4,16,32
                    x[m][4*c+e] = va[e] * v + vb[e] * xp;
                }
            }
        }
    }
}

__device__ __forceinline__ void zwrite(
    float* __restrict__ zz, int lane, const float (&x)[2][16])
{
    // f2-slot pi = pz(c) = c ^ (((c>>4)&7)<<1) for element c = lane*16+k
    const int km0 = (lane & 7) << 1;
    #pragma unroll
    for (int k = 0; k < 16; k += 2) {
        int pi = lane * 16 + (k ^ km0);
        f4 v = { x[0][k], x[1][k], x[0][k+1], x[1][k+1] };
        *reinterpret_cast<f4*>(&zz[2 * pi]) = v;
    }
}

__device__ __forceinline__ void emit(
    const float* __restrict__ zz, const int* __restrict__ src2,
    const float* __restrict__ scale, float* __restrict__ out,
    int s0, int lane)
{
    const i4* srv = reinterpret_cast<const i4*>(src2);
    const f4* scv = reinterpret_cast<const f4*>(scale);
    f4* o0 = reinterpret_cast<f4*>(out + (size_t)s0 * 4096);
    f4* o1 = reinterpret_cast<f4*>(out + (size_t)(s0 + 1) * 4096);

    i4 si = srv[lane];
    f4 sc = scv[lane];
    #pragma unroll
    for (int it = 0; it < 16; ++it) {
        i4 si_c = si;
        f4 sc_c = sc;
        if (it + 1 < 16) {                      // prefetch next iteration
            si = srv[(it + 1) * 64 + lane];
            sc = scv[(it + 1) * 64 + lane];
        }
        int j4 = it * 64 + lane;
        f2 vx = *reinterpret_cast<const f2*>(&zz[2 * si_c.x]);
        f2 vy = *reinterpret_cast<const f2*>(&zz[2 * si_c.y]);
        f2 vz = *reinterpret_cast<const f2*>(&zz[2 * si_c.z]);
        f2 vw = *reinterpret_cast<const f2*>(&zz[2 * si_c.w]);
        f4 r0 = { sc_c.x * vx.x, sc_c.y * vy.x, sc_c.z * vz.x, sc_c.w * vw.x };
        f4 r1 = { sc_c.x * vx.y, sc_c.y * vy.y, sc_c.z * vz.y, sc_c.w * vw.y };
        o0[j4] = r0;
        o1[j4] = r1;
    }
}

__global__ void __launch_bounds__(512, 2) bfly_main(
    const float* __restrict__ inp, const float* __restrict__ lp,
    const float* __restrict__ scale, const int* __restrict__ src2,
    float* __restrict__ out)
{
    // [0, 20480): 20 coeff rows (stages 0..9 a,b), swizzled. persistent.
    // [20480, 36864): 8 waves x 1024 paired-f2 z slots (8 KB each).
    __shared__ __align__(16) float cf[20 * 1024 + 8 * 2048];
    const int t = threadIdx.x;
    const int wave = t >> 6, lane = t & 63;

    // cooperative coeff staging: rows 0..19 of lp (first 1024 floats each);
    // 512 threads stage two rows per step.
    #pragma unroll
    for (int step = 0; step < 10; ++step) {
        const int q = 2 * step + (t >> 8);
        const int e = (t & 255) * 4;
        const f4 v = *reinterpret_cast<const f4*>(lp + (size_t)q * 4096 + e);
        *reinterpret_cast<f4*>(&cf[q * 1024 + swz(e)]) = v;
    }

    const int sBase = blockIdx.x * 32 + wave * 4;   // 4 samples per wave
    float* zz = &cf[20 * 1024 + (size_t)wave * 2048];

    float x[2][16];
    load_chunk(inp, sBase, lane, x);                // chunk 0 input

    __syncthreads();   // cf ready — the only barrier in the kernel

    butterfly(cf, lane, x);
    zwrite(zz, lane, x);

    float y[2][16];
    load_chunk(inp, sBase + 2, lane, y);            // chunk 1 loads in flight

    emit(zz, src2, scale, out, sBase, lane);        // chunk 0 stores || loads

    butterfly(cf, lane, y);                         // || chunk 0 store drain
    zwrite(zz, lane, y);                            // after emit0 reads (in-order DS)
    emit(zz, src2, scale, out, sBase + 2, lane);
}

extern "C" void kernel_launch(void* const* d_in, const int* in_sizes, int n_in,
                              void* d_out, int out_size, void* d_ws, size_t ws_size,
                              hipStream_t stream) {
    const float* inp  = (const float*)d_in[0];   // (8192, 1024) f32
    const float* lp   = (const float*)d_in[1];   // (24, 4096)  f32
    const int*   orow = (const int*)d_in[2];     // (4096,)     i32
    float* out = (float*)d_out;                  // (8192, 4096) f32

    float* scale = (float*)d_ws;                       // 4096 f32
    int*   src2  = (int*)((char*)d_ws + 4096 * 4);     // 4096 i32 (f2-slot idx)

    bfly_prep<<<16, 256, 0, stream>>>(lp, orow, scale, src2);
    bfly_main<<<256, 512, 0, stream>>>(inp, lp, scale, src2, out);
}

// Round 15
// 57.967 us; speedup vs baseline: 2.4128x; 2.4128x over previous
//
#include <hip/hip_runtime.h>

// OurButterflyLayer: N=4096, LOGN=12, IN=1024, OUT=4096, BATCH=8192
//
// out[s,j] = scale[j] * z_s[src[j]],  z_s = 10-stage butterfly (stages 0..9)
// on the 1024-float input row s; stages 10,11 + out-row gather fold into
// per-output (scale, src) pairs (elements >=1024 stay zero through stages
// 0..9 since all strides < 1024).
//
// Round-15: TWO-KERNEL SPLIT (grid-level phase decoupling; intra-wave
// pipelining spills — R11/R14). Kernel A = R13's verified butterfly, dumping
// the paired-swizzled z region (8 KB/pair) linearly to workspace. Kernel B =
// pure streaming gather: copy z region global->LDS linearly (layout
// preserved bit-for-bit) + R7-verified paired emit. Same grid/block shape
// for A and B -> same block->XCD mapping -> B's z reads are L2-local.
// Fallback to the R13 mono kernel if ws_size < 32 MB + 32 KB.

typedef float f4 __attribute__((ext_vector_type(4)));
typedef float f2 __attribute__((ext_vector_type(2)));
typedef int   i4 __attribute__((ext_vector_type(4)));

__device__ __forceinline__ int swz(int e) {
    // XOR float-index bits [6:5] into [3:2]: keeps float4 alignment; makes
    // 64B-stride LDS coeff accesses bank-conflict-free.
    return e ^ (((e >> 5) & 3) << 2);
}

template<int CTRL>
__device__ __forceinline__ float dppx(float x) {
    int xi = __builtin_bit_cast(int, x);
    int r  = __builtin_amdgcn_update_dpp(xi, xi, CTRL, 0xF, 0xF, true);
    return __builtin_bit_cast(float, r);
}
// ctrl: quad_perm(1,0,3,2)=0xB1 (lane^1), quad_perm(2,3,0,1)=0x4E (lane^2),
// row_ror:8=0x128 (lane^8 within 16-lane row). Verified R4/R6/R7/R10/R13.

__global__ void __launch_bounds__(256) bfly_prep(
    const float* __restrict__ lp, const int* __restrict__ orow,
    float* __restrict__ scale, int* __restrict__ src2)
{
    int j = blockIdx.x * 256 + threadIdx.x;
    if (j >= 4096) return;
    int r = orow[j];
    int c = r & 1023;
    int u = r & 2047;
    const float* A10 = lp + 20 * 4096;
    const float* B10 = lp + 21 * 4096;
    const float* A11 = lp + 22 * 4096;
    const float* B11 = lp + 23 * 4096;
    float f11 = (r & 2048) ? B11[u] : A11[u];
    float f10 = (r & 1024) ? B10[c] : A10[c];
    scale[j] = f11 * f10;
    // f2-slot index with pair-preserving bank spread:
    // pz(c) = c ^ (((c>>4)&7)<<1)   (matches zwrite slot algebra below)
    src2[j] = c ^ (((c >> 4) & 7) << 1);
}

__device__ __forceinline__ void stage_coeffs(
    const float* __restrict__ lp, float* __restrict__ cf, int t)
{
    // rows 0..19 of lp (first 1024 floats each); 512 threads, 2 rows/step
    #pragma unroll
    for (int step = 0; step < 10; ++step) {
        const int q = 2 * step + (t >> 8);
        const int e = (t & 255) * 4;
        const f4 v = *reinterpret_cast<const f4*>(lp + (size_t)q * 4096 + e);
        *reinterpret_cast<f4*>(&cf[q * 1024 + swz(e)]) = v;
    }
}

__device__ __forceinline__ void butterfly(
    const float* __restrict__ cf, int lane, float (&x)[2][16])
{
    // ---- stages 0,1 (s=1,2): pairs within each f4 quarter ----
    #pragma unroll
    for (int i = 0; i < 2; ++i) {
        const float* arow = &cf[(size_t)(2*i)     * 1024];
        const float* brow = &cf[(size_t)(2*i + 1) * 1024];
        #pragma unroll
        for (int c = 0; c < 4; ++c) {
            f4 va = *reinterpret_cast<const f4*>(&arow[swz(lane * 16 + 4 * c)]);
            f4 vb = *reinterpret_cast<const f4*>(&brow[swz(lane * 16 + 4 * c)]);
            #pragma unroll
            for (int m = 0; m < 2; ++m) {
                float* xm = x[m];
                if (i == 0) {          // pairs (0,1),(2,3)
                    float lo0 = xm[4*c+0], hi0 = xm[4*c+1];
                    xm[4*c+0] = va[0] * lo0 + vb[1] * hi0;
                    xm[4*c+1] = va[1] * hi0 + vb[0] * lo0;
                    float lo1 = xm[4*c+2], hi1 = xm[4*c+3];
                    xm[4*c+2] = va[2] * lo1 + vb[3] * hi1;
                    xm[4*c+3] = va[3] * hi1 + vb[2] * lo1;
                } else {               // pairs (0,2),(1,3)
                    float lo0 = xm[4*c+0], hi0 = xm[4*c+2];
                    xm[4*c+0] = va[0] * lo0 + vb[2] * hi0;
                    xm[4*c+2] = va[2] * hi0 + vb[0] * lo0;
                    float lo1 = xm[4*c+1], hi1 = xm[4*c+3];
                    xm[4*c+1] = va[1] * lo1 + vb[3] * hi1;
                    xm[4*c+3] = va[3] * hi1 + vb[1] * lo1;
                }
            }
        }
    }

    // ---- stages 2,3 (s=4,8): pairs across quarters ----
    #pragma unroll
    for (int i = 2; i < 4; ++i) {
        const float* arow = &cf[(size_t)(2*i)     * 1024];
        const float* brow = &cf[(size_t)(2*i + 1) * 1024];
        #pragma unroll
        for (int g = 0; g < 2; ++g) {
            const int q0 = (i == 2) ? 2 * g : g;       // s=4: (0,1),(2,3)
            const int q1 = (i == 2) ? q0 + 1 : q0 + 2; // s=8: (0,2),(1,3)
            f4 va0 = *reinterpret_cast<const f4*>(&arow[swz(lane * 16 + 4 * q0)]);
            f4 va1 = *reinterpret_cast<const f4*>(&arow[swz(lane * 16 + 4 * q1)]);
            f4 vb0 = *reinterpret_cast<const f4*>(&brow[swz(lane * 16 + 4 * q0)]);
            f4 vb1 = *reinterpret_cast<const f4*>(&brow[swz(lane * 16 + 4 * q1)]);
            #pragma unroll
            for (int m = 0; m < 2; ++m) {
                float* xm = x[m];
                #pragma unroll
                for (int e = 0; e < 4; ++e) {
                    float lo = xm[4*q0+e], hi = xm[4*q1+e];
                    xm[4*q0+e] = va0[e] * lo + vb1[e] * hi;
                    xm[4*q1+e] = va1[e] * hi + vb0[e] * lo;
                }
            }
        }
    }

    // ---- stage 4 (d=1): DPP quad_perm exchange; coeff rows 8,9 ----
    {
        const float* arow = &cf[(size_t)8 * 1024];
        const float* brow = &cf[(size_t)9 * 1024];
        #pragma unroll
        for (int c = 0; c < 4; ++c) {
            f4 va = *reinterpret_cast<const f4*>(&arow[swz(lane * 16 + 4 * c)]);
            f4 vb = *reinterpret_cast<const f4*>(&brow[swz((lane ^ 1) * 16 + 4 * c)]);
            #pragma unroll
            for (int m = 0; m < 2; ++m) {
                #pragma unroll
                for (int e = 0; e < 4; ++e) {
                    float v = x[m][4*c+e];
                    x[m][4*c+e] = va[e] * v + vb[e] * dppx<0xB1>(v);
                }
            }
        }
    }

    // ---- stages 5..9 (d=2,4,8,16,32): coeff rows 10..19 ----
    #pragma unroll
    for (int i = 5; i < 10; ++i) {
        const int d = 1 << (i - 4);
        const float* arow = &cf[(size_t)(2*i)     * 1024];
        const float* brow = &cf[(size_t)(2*i + 1) * 1024];
        #pragma unroll
        for (int c = 0; c < 4; ++c) {
            f4 va = *reinterpret_cast<const f4*>(&arow[swz(lane * 16 + 4 * c)]);
            f4 vb = *reinterpret_cast<const f4*>(&brow[swz((lane ^ d) * 16 + 4 * c)]);
            #pragma unroll
            for (int m = 0; m < 2; ++m) {
                #pragma unroll
                for (int e = 0; e < 4; ++e) {
                    float v = x[m][4*c+e];
                    float xp = (d == 2) ? dppx<0x4E>(v)
                             : (d == 8) ? dppx<0x128>(v)
                             :            __shfl_xor(v, d, 64);   // d = 4,16,32
                    x[m][4*c+e] = va[e] * v + vb[e] * xp;
                }
            }
        }
    }
}

__device__ __forceinline__ void zwrite(
    float* __restrict__ zz, int lane, const float (&x)[2][16])
{
    // f2-slot pi = pz(c) = c ^ (((c>>4)&7)<<1) for element c = lane*16+k
    const int km0 = (lane & 7) << 1;
    #pragma unroll
    for (int k = 0; k < 16; k += 2) {
        int pi = lane * 16 + (k ^ km0);
        f4 v = { x[0][k], x[1][k], x[0][k+1], x[1][k+1] };
        *reinterpret_cast<f4*>(&zz[2 * pi]) = v;
    }
}

__device__ __forceinline__ void emit(
    const float* __restrict__ zz, const int* __restrict__ src2,
    const float* __restrict__ scale, float* __restrict__ out,
    int s0, int lane)
{
    const i4* srv = reinterpret_cast<const i4*>(src2);
    const f4* scv = reinterpret_cast<const f4*>(scale);
    f4* o0 = reinterpret_cast<f4*>(out + (size_t)s0 * 4096);
    f4* o1 = reinterpret_cast<f4*>(out + (size_t)(s0 + 1) * 4096);

    i4 si = srv[lane];
    f4 sc = scv[lane];
    #pragma unroll
    for (int it = 0; it < 16; ++it) {
        i4 si_c = si;
        f4 sc_c = sc;
        if (it + 1 < 16) {                      // prefetch next iteration
            si = srv[(it + 1) * 64 + lane];
            sc = scv[(it + 1) * 64 + lane];
        }
        int j4 = it * 64 + lane;
        f2 vx = *reinterpret_cast<const f2*>(&zz[2 * si_c.x]);
        f2 vy = *reinterpret_cast<const f2*>(&zz[2 * si_c.y]);
        f2 vz = *reinterpret_cast<const f2*>(&zz[2 * si_c.z]);
        f2 vw = *reinterpret_cast<const f2*>(&zz[2 * si_c.w]);
        f4 r0 = { sc_c.x * vx.x, sc_c.y * vy.x, sc_c.z * vz.x, sc_c.w * vw.x };
        f4 r1 = { sc_c.x * vx.y, sc_c.y * vy.y, sc_c.z * vz.y, sc_c.w * vw.y };
        o0[j4] = r0;
        o1[j4] = r1;
    }
}

// ---------------- Kernel A: butterfly -> paired z to workspace ----------------
__global__ void __launch_bounds__(512, 2) bfly_stageA(
    const float* __restrict__ inp, const float* __restrict__ lp,
    float* __restrict__ z2)
{
    __shared__ __align__(16) float cf[20 * 1024 + 8 * 2048];
    const int t = threadIdx.x;
    const int wave = t >> 6, lane = t & 63;

    stage_coeffs(lp, cf, t);

    const int pair = blockIdx.x * 8 + wave;       // pair = 2 samples
    const int sBase = pair * 2;
    float x[2][16];
    #pragma unroll
    for (int m = 0; m < 2; ++m) {
        const f4* p = reinterpret_cast<const f4*>(inp + (size_t)(sBase + m) * 1024 + lane * 16);
        #pragma unroll
        for (int c = 0; c < 4; ++c) {
            f4 v = __builtin_nontemporal_load(p + c);   // keep L2 for z
            x[m][4*c+0] = v.x; x[m][4*c+1] = v.y; x[m][4*c+2] = v.z; x[m][4*c+3] = v.w;
        }
    }

    __syncthreads();   // cf ready — the only barrier

    butterfly(cf, lane, x);

    float* zz = &cf[20 * 1024 + (size_t)wave * 2048];
    zwrite(zz, lane, x);

    // dump the paired-swizzled region LINEARLY (layout preserved for B)
    float* dst = z2 + (size_t)pair * 2048;
    #pragma unroll
    for (int i = 0; i < 8; ++i) {
        f4 v = *reinterpret_cast<const f4*>(&zz[i * 256 + lane * 4]);
        *reinterpret_cast<f4*>(&dst[i * 256 + lane * 4]) = v;   // plain: land in L2
    }
}

// ---------------- Kernel B: streaming gather/scale ----------------
__global__ void __launch_bounds__(512, 4) bfly_gatherB(
    const float* __restrict__ z2, const float* __restrict__ scale,
    const int* __restrict__ src2, float* __restrict__ out)
{
    __shared__ __align__(16) float zb[8 * 2048];   // 64 KB -> 2 blocks/CU
    const int t = threadIdx.x;
    const int wave = t >> 6, lane = t & 63;
    const int pair = blockIdx.x * 8 + wave;

    float* zz = &zb[(size_t)wave * 2048];
    const float* src = z2 + (size_t)pair * 2048;
    #pragma unroll
    for (int i = 0; i < 8; ++i) {
        f4 v = *reinterpret_cast<const f4*>(&src[i * 256 + lane * 4]);
        *reinterpret_cast<f4*>(&zz[i * 256 + lane * 4]) = v;
    }
    // wave-private region: in-wave lgkmcnt ordering suffices, no barrier
    emit(zz, src2, scale, out, pair * 2, lane);
}

// ---------------- Fallback: R13 mono kernel (verified, 42.5 us) ----------------
__global__ void __launch_bounds__(512, 2) bfly_mono(
    const float* __restrict__ inp, const float* __restrict__ lp,
    const float* __restrict__ scale, const int* __restrict__ src2,
    float* __restrict__ out)
{
    __shared__ __align__(16) float cf[20 * 1024 + 8 * 2048];
    const int t = threadIdx.x;
    const int wave = t >> 6, lane = t & 63;

    stage_coeffs(lp, cf, t);

    const int sBase = blockIdx.x * 16 + wave * 2;
    float x[2][16];
    #pragma unroll
    for (int m = 0; m < 2; ++m) {
        const f4* p = reinterpret_cast<const f4*>(inp + (size_t)(sBase + m) * 1024 + lane * 16);
        #pragma unroll
        for (int c = 0; c < 4; ++c) {
            f4 v = p[c];
            x[m][4*c+0] = v.x; x[m][4*c+1] = v.y; x[m][4*c+2] = v.z; x[m][4*c+3] = v.w;
        }
    }

    __syncthreads();

    butterfly(cf, lane, x);
    float* zz = &cf[20 * 1024 + (size_t)wave * 2048];
    zwrite(zz, lane, x);
    emit(zz, src2, scale, out, sBase, lane);
}

extern "C" void kernel_launch(void* const* d_in, const int* in_sizes, int n_in,
                              void* d_out, int out_size, void* d_ws, size_t ws_size,
                              hipStream_t stream) {
    const float* inp  = (const float*)d_in[0];   // (8192, 1024) f32
    const float* lp   = (const float*)d_in[1];   // (24, 4096)  f32
    const int*   orow = (const int*)d_in[2];     // (4096,)     i32
    float* out = (float*)d_out;                  // (8192, 4096) f32

    float* scale = (float*)d_ws;                            // 4096 f32 (16 KB)
    int*   src2  = (int*)((char*)d_ws + 16384);             // 4096 i32 (16 KB)
    float* z2    = (float*)((char*)d_ws + 32768);           // 4096 pairs x 2048 f32 = 32 MB

    const size_t need = 32768 + (size_t)4096 * 2048 * 4;

    bfly_prep<<<16, 256, 0, stream>>>(lp, orow, scale, src2);
    if (ws_size >= need) {
        bfly_stageA <<<512, 512, 0, stream>>>(inp, lp, z2);
        bfly_gatherB<<<512, 512, 0, stream>>>(z2, scale, src2, out);
    } else {
        bfly_mono<<<512, 512, 0, stream>>>(inp, lp, scale, src2, out);
    }
}